// Round 3
// baseline (148.425 us; speedup 1.0000x reference)
//
#include <hip/hip_runtime.h>
#include <math.h>

#define NE 16   // electrons
#define NA 4    // atoms
#define NB 4    // basis
#define NK 8    // kernel
#define NM 16   // embed
#define NL 2    // layers

typedef float f32x2 __attribute__((ext_vector_type(2)));

__device__ __forceinline__ float ssp(float x) {
    // softplus(x) - ln2 == max(x,0) + ln2*log2(1 + 2^(-|x|*log2e)) - ln2
    float t  = __builtin_amdgcn_exp2f(-1.44269504088896f * fabsf(x)); // e^{-|x|}, in (0,1]
    float lg = __builtin_amdgcn_logf(1.0f + t);                       // log2(1+t)
    return fmaf(0.69314718055995f, lg, fmaxf(x, 0.0f) - 0.69314718055995f);
}

// One wave (64 threads) per batch element. lane = (i electron 0..15, q quarter 0..3).
// Single-wave blocks: barriers are intra-wave only (cheap), 8192 blocks give the
// scheduler fine-grained packing (fixes the 37% occupancy / exact-fill tail of the
// 256-thread version).
__global__ void __launch_bounds__(64) jastrow_kernel(
    const float* __restrict__ edges_elec,  // [B,16,16,4]
    const float* __restrict__ edges_nuc,   // [B,16,4,4]
    const float* __restrict__ x_init,      // [16,16]
    const float* __restrict__ Y,           // [4,8]
    const float* __restrict__ wW1,         // [2,3,4,8]
    const float* __restrict__ wb1,         // [2,3,8]
    const float* __restrict__ wW2,         // [2,3,8,8]
    const float* __restrict__ wb2,         // [2,3,8]
    const float* __restrict__ hW,          // [2,16,8]
    const float* __restrict__ hb,          // [2,8]
    const float* __restrict__ gW1,         // [2,3,8,8]
    const float* __restrict__ gb1,         // [2,3,8]
    const float* __restrict__ gW2,         // [2,3,8,16]
    const float* __restrict__ gb2,         // [2,3,16]
    const float* __restrict__ oW,          // [16]
    const float* __restrict__ ob,          // [1]
    float* __restrict__ out, int B)
{
    __shared__ f32x2 hx2_lds[NE][4];       // per-wave hx broadcast (512 B)

    const int lane = threadIdx.x & 63;
    const int i    = lane >> 2;            // electron row 0..15
    const int q    = lane & 3;             // quarter-lane 0..3

    int b = blockIdx.x;
    if (b >= B) b = B - 1;

    const int sbase = (i < 8) ? 0 : 8;     // same-spin j block
    const int abase = (i < 8) ? 8 : 0;     // anti-spin j block

    // ---- load all edge features for this lane's pairs once (reused across layers) ----
    const float4* Ee = reinterpret_cast<const float4*>(edges_elec) + (size_t)b * (NE * NE);
    const float4 Es0 = Ee[i * NE + sbase + q];
    const float4 Es1 = Ee[i * NE + sbase + q + 4];
    const float4 Ea0 = Ee[i * NE + abase + q];
    const float4 Ea1 = Ee[i * NE + abase + q + 4];
    const float4* En = reinterpret_cast<const float4*>(edges_nuc) + (size_t)b * (NE * NA);
    const float4 Enu = En[i * NA + q];

    // ---- x: lane owns x[i][q*4 .. q*4+3] as 2x f32x2 ----
    f32x2 xe[2];
    {
        const f32x2* Xi = reinterpret_cast<const f32x2*>(x_init + i * NM + q * 4);
        xe[0] = Xi[0]; xe[1] = Xi[1];
    }

    // filter subnet: t2 = ssp(e @ W1 + b1) @ W2 + b2 (k processed as f32x2 pairs)
    auto filt = [&](const float4& e, int lc, f32x2 (&t2)[4]) {
        const f32x2* W1 = reinterpret_cast<const f32x2*>(wW1 + lc * NB * NK);
        const f32x2* B1 = reinterpret_cast<const f32x2*>(wb1 + lc * NK);
        const f32x2* W2 = reinterpret_cast<const f32x2*>(wW2 + lc * NK * NK);
        const f32x2* B2 = reinterpret_cast<const f32x2*>(wb2 + lc * NK);
        float s[NK];
        #pragma unroll
        for (int k2 = 0; k2 < 4; ++k2) {
            f32x2 a = B1[k2];
            a += e.x * W1[0 * 4 + k2];
            a += e.y * W1[1 * 4 + k2];
            a += e.z * W1[2 * 4 + k2];
            a += e.w * W1[3 * 4 + k2];
            s[2 * k2]     = ssp(a.x);
            s[2 * k2 + 1] = ssp(a.y);
        }
        #pragma unroll
        for (int k2 = 0; k2 < 4; ++k2) {
            f32x2 a = B2[k2];
            #pragma unroll
            for (int kk = 0; kk < NK; ++kk)
                a += s[kk] * W2[kk * 4 + k2];
            t2[k2] = a;
        }
    };

    #pragma unroll
    for (int l = 0; l < NL; ++l) {
        // ---- hx = x @ hW + hb : partials over lane's 4 embed dims, butterfly over q ----
        f32x2 hx2[4];
        {
            const f32x2* Hw = reinterpret_cast<const f32x2*>(hW + l * NM * NK);
            #pragma unroll
            for (int k2 = 0; k2 < 4; ++k2) {
                f32x2 a = xe[0].x * Hw[(q * 4 + 0) * 4 + k2];
                a += xe[0].y * Hw[(q * 4 + 1) * 4 + k2];
                a += xe[1].x * Hw[(q * 4 + 2) * 4 + k2];
                a += xe[1].y * Hw[(q * 4 + 3) * 4 + k2];
                hx2[k2] = a;
            }
        }
        {
            const f32x2* Hb = reinterpret_cast<const f32x2*>(hb + l * NK);
            #pragma unroll
            for (int k2 = 0; k2 < 4; ++k2) {
                hx2[k2].x += __shfl_xor(hx2[k2].x, 1);
                hx2[k2].x += __shfl_xor(hx2[k2].x, 2);
                hx2[k2].y += __shfl_xor(hx2[k2].y, 1);
                hx2[k2].y += __shfl_xor(hx2[k2].y, 2);
                hx2[k2] += Hb[k2];         // bias AFTER the q-reduction
            }
        }
        __syncthreads();                   // 1-wave barrier: WAR on hx2_lds (cheap)
        hx2_lds[i][q] = hx2[q];            // 4 lanes of the q-group cover k=0..7
        __syncthreads();                   // writes visible before cross-lane reads

        f32x2 z0[4] = {{0,0},{0,0},{0,0},{0,0}};  // same-spin channel
        f32x2 z1[4] = {{0,0},{0,0},{0,0},{0,0}};  // anti-spin channel
        f32x2 zn[4];                               // nuclear channel

        // ---- same-spin pairs (channel 0): j = sbase + q + 4t, diagonal masked ----
        #pragma unroll
        for (int t = 0; t < 2; ++t) {
            const int j = sbase + q + 4 * t;
            f32x2 t2[4];
            filt((t == 0) ? Es0 : Es1, l * 3 + 0, t2);
            const float msk = (j == i) ? 0.f : 1.f;
            #pragma unroll
            for (int k2 = 0; k2 < 4; ++k2)
                z0[k2] += (msk * t2[k2]) * hx2_lds[j][k2];
        }
        // ---- anti-spin pairs (channel 1): j = abase + q + 4t ----
        #pragma unroll
        for (int t = 0; t < 2; ++t) {
            const int j = abase + q + 4 * t;
            f32x2 t2[4];
            filt((t == 0) ? Ea0 : Ea1, l * 3 + 1, t2);
            #pragma unroll
            for (int k2 = 0; k2 < 4; ++k2)
                z1[k2] += t2[k2] * hx2_lds[j][k2];
        }
        // ---- nuclear channel (2): atom a = q ----
        {
            f32x2 t2[4];
            filt(Enu, l * 3 + 2, t2);
            const f32x2* Yv = reinterpret_cast<const f32x2*>(Y + q * NK);
            #pragma unroll
            for (int k2 = 0; k2 < 4; ++k2)
                zn[k2] = t2[k2] * Yv[k2];
        }

        // ---- reduce z over the 4-lane q-group (sums each channel over its j/a subsets) ----
        float zr0[NK], zr1[NK], zrn[NK];
        #pragma unroll
        for (int k2 = 0; k2 < 4; ++k2) {
            float a;
            a = z0[k2].x; a += __shfl_xor(a, 1); a += __shfl_xor(a, 2); zr0[2*k2]   = a;
            a = z0[k2].y; a += __shfl_xor(a, 1); a += __shfl_xor(a, 2); zr0[2*k2+1] = a;
            a = z1[k2].x; a += __shfl_xor(a, 1); a += __shfl_xor(a, 2); zr1[2*k2]   = a;
            a = z1[k2].y; a += __shfl_xor(a, 1); a += __shfl_xor(a, 2); zr1[2*k2+1] = a;
            a = zn[k2].x; a += __shfl_xor(a, 1); a += __shfl_xor(a, 2); zrn[2*k2]   = a;
            a = zn[k2].y; a += __shfl_xor(a, 1); a += __shfl_xor(a, 2); zrn[2*k2+1] = a;
        }

        // ---- g-nets: upd[i][e] for lane's 4 embed dims e = q*4+m ----
        f32x2 upd[2] = {{0,0},{0,0}};
        auto gnet = [&](const float (&z)[NK], int lc) {
            const f32x2* G1  = reinterpret_cast<const f32x2*>(gW1 + lc * NK * NK);
            const f32x2* Gb1 = reinterpret_cast<const f32x2*>(gb1 + lc * NK);
            float g[NK];
            #pragma unroll
            for (int k2 = 0; k2 < 4; ++k2) {
                f32x2 a = Gb1[k2];
                #pragma unroll
                for (int k = 0; k < NK; ++k)
                    a += z[k] * G1[k * 4 + k2];
                g[2 * k2]     = ssp(a.x);
                g[2 * k2 + 1] = ssp(a.y);
            }
            const f32x2* G2  = reinterpret_cast<const f32x2*>(gW2 + lc * NK * NM);
            const f32x2* Gb2 = reinterpret_cast<const f32x2*>(gb2 + lc * NM);
            #pragma unroll
            for (int m2 = 0; m2 < 2; ++m2) {
                f32x2 a = Gb2[q * 2 + m2];
                #pragma unroll
                for (int kk = 0; kk < NK; ++kk)
                    a += g[kk] * G2[kk * 8 + q * 2 + m2];
                upd[m2] += a;
            }
        };
        gnet(zr0, l * 3 + 0);
        gnet(zr1, l * 3 + 1);
        gnet(zrn, l * 3 + 2);

        xe[0] += upd[0];
        xe[1] += upd[1];
    }

    // ---- readout: sum_{i,e} x[i][e]*oW[e] + 16*ob ----
    const f32x2* O2 = reinterpret_cast<const f32x2*>(oW + q * 4);
    f32x2 p2 = xe[0] * O2[0] + xe[1] * O2[1];
    float part = p2.x + p2.y;
    #pragma unroll
    for (int off = 1; off < 64; off <<= 1) part += __shfl_xor(part, off);

    if (lane == 0 && blockIdx.x < B) out[b] = part + 16.f * ob[0];
}

extern "C" void kernel_launch(void* const* d_in, const int* in_sizes, int n_in,
                              void* d_out, int out_size, void* d_ws, size_t ws_size,
                              hipStream_t stream) {
    const float* edges_elec = (const float*)d_in[0];
    const float* edges_nuc  = (const float*)d_in[1];
    const float* x_init     = (const float*)d_in[2];
    const float* Yp         = (const float*)d_in[3];
    const float* wW1        = (const float*)d_in[4];
    const float* wb1        = (const float*)d_in[5];
    const float* wW2        = (const float*)d_in[6];
    const float* wb2        = (const float*)d_in[7];
    const float* hW         = (const float*)d_in[8];
    const float* hb         = (const float*)d_in[9];
    const float* gW1        = (const float*)d_in[10];
    const float* gb1        = (const float*)d_in[11];
    const float* gW2        = (const float*)d_in[12];
    const float* gb2        = (const float*)d_in[13];
    const float* oW         = (const float*)d_in[14];
    const float* ob         = (const float*)d_in[15];
    float* out = (float*)d_out;

    const int B = in_sizes[0] / (NE * NE * NB);   // 8192
    // one wave = one batch element; single-wave blocks for scheduling freedom
    hipLaunchKernelGGL(jastrow_kernel, dim3(B), dim3(64), 0, stream,
                       edges_elec, edges_nuc, x_init, Yp, wW1, wb1, wW2, wb2,
                       hW, hb, gW1, gb1, gW2, gb2, oW, ob, out, B);
}

// Round 12
// 146.927 us; speedup vs baseline: 1.0102x; 1.0102x over previous
//
#include <hip/hip_runtime.h>
#include <math.h>

#define NE 16   // electrons
#define NA 4    // atoms
#define NB 4    // basis
#define NK 8    // kernel
#define NM 16   // embed
#define NL 2    // layers

typedef float f32x2 __attribute__((ext_vector_type(2)));

__device__ __forceinline__ float ssp(float x) {
    // softplus(x) - ln2 = max(x,0) + ln2*log2(1 + 2^(-|x|*log2e)) - ln2  (overflow-safe)
    float t  = __builtin_amdgcn_exp2f(-1.44269504088896f * fabsf(x));
    float lg = __builtin_amdgcn_logf(1.0f + t);
    return fmaf(0.69314718055995f, lg, fmaxf(x, 0.0f) - 0.69314718055995f);
}

__device__ __forceinline__ f32x2 qreduce(f32x2 v) {   // sum over the 4-lane q-group (DPP quad_perm)
    v.x += __shfl_xor(v.x, 1); v.y += __shfl_xor(v.y, 1);
    v.x += __shfl_xor(v.x, 2); v.y += __shfl_xor(v.y, 2);
    return v;
}

// One wave per batch element. lane = (i electron 0..15, q quarter 0..3).
// vs v3: the g-net first stage is split 4-ways across the q-group (each lane
// computes only g[2q],g[2q+1] per channel: 8 pk-FMA + 2 ssp instead of the
// 4x-redundant 64 FMA + 8 ssp), with g[8] regathered by address via LDS.
// NOTE: z must be q-reduced BEFORE the G1 projection — the projection columns
// are q-dependent, so partial-sums don't commute past it (bug found in v4).
__global__ void __launch_bounds__(64) jastrow_kernel(
    const float* __restrict__ edges_elec,  // [B,16,16,4]
    const float* __restrict__ edges_nuc,   // [B,16,4,4]
    const float* __restrict__ x_init,      // [16,16]
    const float* __restrict__ Y,           // [4,8]
    const float* __restrict__ wW1,         // [2,3,4,8]
    const float* __restrict__ wb1,         // [2,3,8]
    const float* __restrict__ wW2,         // [2,3,8,8]
    const float* __restrict__ wb2,         // [2,3,8]
    const float* __restrict__ hW,          // [2,16,8]
    const float* __restrict__ hb,          // [2,8]
    const float* __restrict__ gW1,         // [2,3,8,8]
    const float* __restrict__ gb1,         // [2,3,8]
    const float* __restrict__ gW2,         // [2,3,8,16]
    const float* __restrict__ gb2,         // [2,3,16]
    const float* __restrict__ oW,          // [16]
    const float* __restrict__ ob,          // [1]
    float* __restrict__ out, int B)
{
    __shared__ f32x2 hx_lds[NE][5];        // padded stride 5 (40 B) rows
    __shared__ f32x2 g_lds[NE][3][4];      // g gather buffer [i][channel][k-pair]

    const int lane = threadIdx.x & 63;
    const int i    = lane >> 2;            // electron 0..15
    const int q    = lane & 3;             // quarter-lane 0..3

    int b = blockIdx.x;
    if (b >= B) b = B - 1;

    const int sbase = (i < 8) ? 0 : 8;
    const int abase = (i < 8) ? 8 : 0;
    const float msk0 = ((i & 7) == q)       ? 0.f : 1.f;  // diagonal j==i in t=0 slot
    const float msk1 = ((i & 7) == (q + 4)) ? 0.f : 1.f;  // diagonal j==i in t=1 slot

    // ---- edges: 5 float4 per lane, reused across both layers ----
    const float4* Ee = reinterpret_cast<const float4*>(edges_elec) + (size_t)b * (NE * NE);
    const float4 Es0 = Ee[i * NE + sbase + q];
    const float4 Es1 = Ee[i * NE + sbase + q + 4];
    const float4 Ea0 = Ee[i * NE + abase + q];
    const float4 Ea1 = Ee[i * NE + abase + q + 4];
    const float4* En = reinterpret_cast<const float4*>(edges_nuc) + (size_t)b * (NE * NA);
    const float4 Enu = En[i * NA + q];

    // ---- Y row for this lane's atom (reused both layers) ----
    const f32x2* Yr = reinterpret_cast<const f32x2*>(Y + q * NK);
    const f32x2 Yq0 = Yr[0], Yq1 = Yr[1], Yq2 = Yr[2], Yq3 = Yr[3];

    // ---- x: lane owns x[i][q*4 .. q*4+3] ----
    f32x2 xe[2];
    {
        const f32x2* Xi = reinterpret_cast<const f32x2*>(x_init + i * NM + q * 4);
        xe[0] = Xi[0]; xe[1] = Xi[1];
    }

    // filter subnet: t2 = ssp(e @ W1 + b1) @ W2 + b2
    auto filt = [&](const float4& e, int lc, f32x2 (&t2)[4]) {
        const f32x2* W1 = reinterpret_cast<const f32x2*>(wW1 + lc * NB * NK);
        const f32x2* B1 = reinterpret_cast<const f32x2*>(wb1 + lc * NK);
        const f32x2* W2 = reinterpret_cast<const f32x2*>(wW2 + lc * NK * NK);
        const f32x2* B2 = reinterpret_cast<const f32x2*>(wb2 + lc * NK);
        float s[NK];
        #pragma unroll
        for (int k2 = 0; k2 < 4; ++k2) {
            f32x2 a = B1[k2];
            a += e.x * W1[0 * 4 + k2];
            a += e.y * W1[1 * 4 + k2];
            a += e.z * W1[2 * 4 + k2];
            a += e.w * W1[3 * 4 + k2];
            s[2 * k2]     = ssp(a.x);
            s[2 * k2 + 1] = ssp(a.y);
        }
        #pragma unroll
        for (int k2 = 0; k2 < 4; ++k2) {
            f32x2 a = B2[k2];
            #pragma unroll
            for (int kk = 0; kk < NK; ++kk)
                a += s[kk] * W2[kk * 4 + k2];
            t2[k2] = a;
        }
    };

    #pragma unroll
    for (int l = 0; l < NL; ++l) {
        // ================= hx = x @ hW + hb =================
        f32x2 hx2[4];
        {
            const f32x2* Hw = reinterpret_cast<const f32x2*>(hW + l * NM * NK);
            #pragma unroll
            for (int k2 = 0; k2 < 4; ++k2) {
                f32x2 a = xe[0].x * Hw[(q * 4 + 0) * 4 + k2];
                a += xe[0].y * Hw[(q * 4 + 1) * 4 + k2];
                a += xe[1].x * Hw[(q * 4 + 2) * 4 + k2];
                a += xe[1].y * Hw[(q * 4 + 3) * 4 + k2];
                hx2[k2] = a;
            }
            const f32x2* Hb = reinterpret_cast<const f32x2*>(hb + l * NK);
            #pragma unroll
            for (int k2 = 0; k2 < 4; ++k2)
                hx2[k2] = qreduce(hx2[k2]) + Hb[k2];
        }
        // write own k-pair: explicit 2-level select (NO runtime register index)
        {
            f32x2 own = (q & 2) ? ((q & 1) ? hx2[3] : hx2[2])
                                : ((q & 1) ? hx2[1] : hx2[0]);
            __syncthreads();               // WAR vs prior layer readers (1-wave: cheap)
            hx_lds[i][q] = own;
            __syncthreads();
        }

        // ================= filters + z partials over this lane's j-subset =================
        f32x2 z0[4], z1[4], zn[4];
        {   // same-spin channel (c=0): pairs j0=sbase+q, j1=sbase+q+4
            f32x2 t2a[4], t2b[4];
            filt(Es0, l * 3 + 0, t2a);
            filt(Es1, l * 3 + 0, t2b);
            const f32x2* h0 = &hx_lds[sbase + q][0];
            const f32x2* h1 = &hx_lds[sbase + q + 4][0];
            #pragma unroll
            for (int k2 = 0; k2 < 4; ++k2)
                z0[k2] = (t2a[k2] * msk0) * h0[k2] + (t2b[k2] * msk1) * h1[k2];
        }
        {   // anti-spin channel (c=1): pairs abase+q, abase+q+4
            f32x2 t2a[4], t2b[4];
            filt(Ea0, l * 3 + 1, t2a);
            filt(Ea1, l * 3 + 1, t2b);
            const f32x2* h0 = &hx_lds[abase + q][0];
            const f32x2* h1 = &hx_lds[abase + q + 4][0];
            #pragma unroll
            for (int k2 = 0; k2 < 4; ++k2)
                z1[k2] = t2a[k2] * h0[k2] + t2b[k2] * h1[k2];
        }
        {   // nuclear channel (c=2): atom a=q
            f32x2 t2[4];
            filt(Enu, l * 3 + 2, t2);
            zn[0] = t2[0] * Yq0; zn[1] = t2[1] * Yq1;
            zn[2] = t2[2] * Yq2; zn[3] = t2[3] * Yq3;
        }

        // ===== q-reduce z FIRST (full z in every lane; required before col-split G1) =====
        #pragma unroll
        for (int k2 = 0; k2 < 4; ++k2) {
            z0[k2] = qreduce(z0[k2]);
            z1[k2] = qreduce(z1[k2]);
            zn[k2] = qreduce(zn[k2]);
        }

        // ===== G1: lane computes only its own columns g[2q], g[2q+1] per channel =====
        f32x2 g2c[3];
        #pragma unroll
        for (int c = 0; c < 3; ++c) {
            const int lc = l * 3 + c;
            const f32x2* G1 = reinterpret_cast<const f32x2*>(gW1 + lc * NK * NK);
            const f32x2* zc = (c == 0) ? z0 : (c == 1) ? z1 : zn;
            const f32x2* B1 = reinterpret_cast<const f32x2*>(gb1 + lc * NK);
            f32x2 a = B1[q];
            a += zc[0].x * G1[0 * 4 + q];
            a += zc[0].y * G1[1 * 4 + q];
            a += zc[1].x * G1[2 * 4 + q];
            a += zc[1].y * G1[3 * 4 + q];
            a += zc[2].x * G1[4 * 4 + q];
            a += zc[2].y * G1[5 * 4 + q];
            a += zc[3].x * G1[6 * 4 + q];
            a += zc[3].y * G1[7 * 4 + q];
            g2c[c].x = ssp(a.x);
            g2c[c].y = ssp(a.y);
        }

        // ===== gather full g[8] per channel via LDS (by-address: no permutation issue) =====
        __syncthreads();                   // WAR vs prior layer's g reads
        g_lds[i][0][q] = g2c[0];
        g_lds[i][1][q] = g2c[1];
        g_lds[i][2][q] = g2c[2];
        __syncthreads();

        // ===== G2: upd for lane's 4 embed dims =====
        f32x2 upd0 = {0.f, 0.f}, upd1 = {0.f, 0.f};
        #pragma unroll
        for (int c = 0; c < 3; ++c) {
            const int lc = l * 3 + c;
            const f32x2 ga = g_lds[i][c][0];
            const f32x2 gb = g_lds[i][c][1];
            const f32x2 gc = g_lds[i][c][2];
            const f32x2 gd = g_lds[i][c][3];
            const f32x2* G2 = reinterpret_cast<const f32x2*>(gW2 + lc * NK * NM + q * 4);
            upd0 += ga.x * G2[0 * 8 + 0];  upd1 += ga.x * G2[0 * 8 + 1];
            upd0 += ga.y * G2[1 * 8 + 0];  upd1 += ga.y * G2[1 * 8 + 1];
            upd0 += gb.x * G2[2 * 8 + 0];  upd1 += gb.x * G2[2 * 8 + 1];
            upd0 += gb.y * G2[3 * 8 + 0];  upd1 += gb.y * G2[3 * 8 + 1];
            upd0 += gc.x * G2[4 * 8 + 0];  upd1 += gc.x * G2[4 * 8 + 1];
            upd0 += gc.y * G2[5 * 8 + 0];  upd1 += gc.y * G2[5 * 8 + 1];
            upd0 += gd.x * G2[6 * 8 + 0];  upd1 += gd.x * G2[6 * 8 + 1];
            upd0 += gd.y * G2[7 * 8 + 0];  upd1 += gd.y * G2[7 * 8 + 1];
            const f32x2* B2 = reinterpret_cast<const f32x2*>(gb2 + lc * NM + q * 4);
            upd0 += B2[0];
            upd1 += B2[1];
        }
        xe[0] += upd0;
        xe[1] += upd1;
    }

    // ---- readout: sum_{i,e} x[i][e]*oW[e] + 16*ob ----
    const f32x2* O2 = reinterpret_cast<const f32x2*>(oW + q * 4);
    f32x2 p2 = xe[0] * O2[0] + xe[1] * O2[1];
    float part = p2.x + p2.y;
    #pragma unroll
    for (int off = 1; off < 64; off <<= 1) part += __shfl_xor(part, off);

    if (lane == 0 && blockIdx.x < B) out[b] = part + 16.f * ob[0];
}

extern "C" void kernel_launch(void* const* d_in, const int* in_sizes, int n_in,
                              void* d_out, int out_size, void* d_ws, size_t ws_size,
                              hipStream_t stream) {
    const float* edges_elec = (const float*)d_in[0];
    const float* edges_nuc  = (const float*)d_in[1];
    const float* x_init     = (const float*)d_in[2];
    const float* Yp         = (const float*)d_in[3];
    const float* wW1        = (const float*)d_in[4];
    const float* wb1        = (const float*)d_in[5];
    const float* wW2        = (const float*)d_in[6];
    const float* wb2        = (const float*)d_in[7];
    const float* hW         = (const float*)d_in[8];
    const float* hb         = (const float*)d_in[9];
    const float* gW1        = (const float*)d_in[10];
    const float* gb1        = (const float*)d_in[11];
    const float* gW2        = (const float*)d_in[12];
    const float* gb2        = (const float*)d_in[13];
    const float* oW         = (const float*)d_in[14];
    const float* ob         = (const float*)d_in[15];
    float* out = (float*)d_out;

    const int B = in_sizes[0] / (NE * NE * NB);   // 8192
    hipLaunchKernelGGL(jastrow_kernel, dim3(B), dim3(64), 0, stream,
                       edges_elec, edges_nuc, x_init, Yp, wW1, wb1, wW2, wb2,
                       hW, hb, gW1, gb1, gW2, gb2, oW, ob, out, B);
}